// Round 1
// 264.313 us; speedup vs baseline: 1.1723x; 1.1723x over previous
//
#include <hip/hip_runtime.h>
#include <hip/hip_bf16.h>

// B=16, C=512, H=W=32 -> P=1024 pixels, 8 groups (64 ch), 8 heads (hd=64).
// Inputs f32, output f32.  Internals bf16 + fp32 accum (validated R6/R8).
// R9: fattn q-tile 128 / 8 waves (16 waves/CU), T14 async K/V prefetch,
//     exp2-domain softmax, setprio around MFMA; GEMMs get reg-prefetch +
//     setprio; gn_stats split to 512 blocks with partials combined in conv_x.
#define BB   16
#define CCH  512
#define PP   1024
#define NHD  8

typedef unsigned short u16;
typedef unsigned int   u32;
typedef __attribute__((ext_vector_type(8))) short bf16x8;   // 8 bf16 = 4 VGPR
typedef __attribute__((ext_vector_type(4))) float f32x4;

__device__ __forceinline__ float us2f(u16 u) {
    return __uint_as_float(((u32)u) << 16);
}
__device__ __forceinline__ u16 f2bu(float f) {
    __hip_bfloat16 h = __float2bfloat16(f);   // RNE
    return *reinterpret_cast<u16*>(&h);
}

// ---------------------------------------------------------------------------
// Kernel 1: partial sums for per-(batch,group) stats.  512 blocks x 256 thr
// (4 partials per bg so all 256 CUs are active; conv_x combines).
// ---------------------------------------------------------------------------
__launch_bounds__(256)
__global__ void gn_stats_k(const float* __restrict__ x,
                           float* __restrict__ ps, float* __restrict__ pss) {
    int blk = blockIdx.x;              // 512 = 128 bg * 4 parts
    int bg = blk >> 2, part = blk & 3;
    const float4* xp = (const float4*)(x + (size_t)bg * 65536 + (size_t)part * 16384);
    float s = 0.f, ss = 0.f;
    for (int i = threadIdx.x; i < 4096; i += 256) {
        float4 v = xp[i];
        s  += v.x + v.y + v.z + v.w;
        ss += v.x*v.x + v.y*v.y + v.z*v.z + v.w*v.w;
    }
    __shared__ float sh[256], sq[256];
    sh[threadIdx.x] = s; sq[threadIdx.x] = ss;
    __syncthreads();
    for (int off = 128; off > 0; off >>= 1) {
        if (threadIdx.x < off) {
            sh[threadIdx.x] += sh[threadIdx.x + off];
            sq[threadIdx.x] += sq[threadIdx.x + off];
        }
        __syncthreads();
    }
    if (threadIdx.x == 0) {
        ps[blk]  = sh[0];
        pss[blk] = sq[0];
    }
}

// ---------------------------------------------------------------------------
// Kernel 2: GN-normalize + convert + transpose: x[b][c][p] f32 ->
// xbt[b][p][c] bf16.  Combines the 4 stat partials (uniform -> SGPR loads).
// ---------------------------------------------------------------------------
__launch_bounds__(256)
__global__ void conv_x_k(const float* __restrict__ x,
                         const float* __restrict__ ps, const float* __restrict__ pss,
                         const float* __restrict__ gamma, const float* __restrict__ beta,
                         u16* __restrict__ xbt) {
    __shared__ u16 T[64][73];
    const int tid = threadIdx.x;
    const int p0 = blockIdx.x * 64;
    const int c0 = blockIdx.y * 64;
    const int b  = blockIdx.z;
    const int bg = (b << 3) + (c0 >> 6);      // uniform per block
    float s4  = ps[bg*4]  + ps[bg*4+1]  + ps[bg*4+2]  + ps[bg*4+3];
    float ss4 = pss[bg*4] + pss[bg*4+1] + pss[bg*4+2] + pss[bg*4+3];
    float m   = s4 * (1.f / 65536.f);
    float var = ss4 * (1.f / 65536.f) - m * m;
    float rs  = rsqrtf(var + 1e-5f);
    {
        int ci = tid >> 2, psx = (tid & 3) * 16;
        int c = c0 + ci;
        float sc = rs * gamma[c];
        float sf = beta[c] - m * sc;
        const float* xp = x + ((size_t)(b * CCH + c)) * PP + p0 + psx;
        #pragma unroll
        for (int j4 = 0; j4 < 4; j4++) {
            float4 v = *(const float4*)(xp + j4 * 4);
            T[psx + j4*4 + 0][ci] = f2bu(v.x * sc + sf);
            T[psx + j4*4 + 1][ci] = f2bu(v.y * sc + sf);
            T[psx + j4*4 + 2][ci] = f2bu(v.z * sc + sf);
            T[psx + j4*4 + 3][ci] = f2bu(v.w * sc + sf);
        }
    }
    __syncthreads();
    {
        int pi = tid >> 2, cs = (tid & 3) * 16;
        u16* dst = xbt + ((size_t)(b * PP) + p0 + pi) * CCH + c0 + cs;
        #pragma unroll
        for (int j4 = 0; j4 < 4; j4++) {
            ushort4 o;
            o.x = T[pi][cs + j4*4 + 0]; o.y = T[pi][cs + j4*4 + 1];
            o.z = T[pi][cs + j4*4 + 2]; o.w = T[pi][cs + j4*4 + 3];
            *(ushort4*)(dst + j4 * 4) = o;
        }
    }
}

// ---------------------------------------------------------------------------
// Kernel 3: weights f32 -> bf16.
// ---------------------------------------------------------------------------
__launch_bounds__(256)
__global__ void conv_w_k(const float* __restrict__ w1, const float* __restrict__ w2,
                         u16* __restrict__ d1, u16* __restrict__ d2) {
    int id = blockIdx.x * 256 + threadIdx.x;
    const float* s; u16* d; int off;
    if (id < 196608) { s = w1; d = d1; off = id * 4; }
    else             { s = w2; d = d2; off = (id - 196608) * 4; }
    float4 v = *(const float4*)(s + off);
    ushort4 o;
    o.x = f2bu(v.x); o.y = f2bu(v.y); o.z = f2bu(v.z); o.w = f2bu(v.w);
    *(ushort4*)(d + off) = o;
}

// ---------------------------------------------------------------------------
// Kernel 4: qkv MFMA GEMM.  R9: next-k reg prefetch (T14) + setprio (T5).
// ---------------------------------------------------------------------------
__launch_bounds__(256)
__global__ void mgemm_qkv_k(const u16* __restrict__ Wb, const float* __restrict__ bias,
                            const u16* __restrict__ actT,
                            u16* __restrict__ qT, u16* __restrict__ kT,
                            u16* __restrict__ v) {
    __shared__ __align__(16) u16 smem[17408];    // staging 2x5120 | Cb 128x136
    u16* As = smem;                              // [128][40]
    u16* Bs = smem + 5120;                       // [128][40]
    const int tid = threadIdx.x;
    const int p0 = blockIdx.x * 128;
    const int m0 = blockIdx.y * 128;
    const int b  = blockIdx.z;
    const int w = tid >> 6, l = tid & 63, quad = l >> 4, lm = l & 15;
    const int mo = (w >> 1) * 64, no = (w & 1) * 64;

    f32x4 acc[4][4] = {};

    const int srow = tid >> 1, sks = (tid & 1) << 4;
    const u16* wp = Wb + (size_t)(m0 + srow) * CCH + sks;
    const u16* ap = actT + (size_t)b * PP * CCH + (size_t)(p0 + srow) * CCH + sks;
    u16* asw = &As[srow * 40 + sks];
    u16* bsw = &Bs[srow * 40 + sks];

    uint4 aw0 = *(const uint4*)(wp);
    uint4 aw1 = *(const uint4*)(wp + 8);
    uint4 bw0 = *(const uint4*)(ap);
    uint4 bw1 = *(const uint4*)(ap + 8);

    for (int k0 = 0; k0 < CCH; k0 += 32) {
        *(uint4*)asw = aw0;  *(uint4*)(asw + 8) = aw1;
        *(uint4*)bsw = bw0;  *(uint4*)(bsw + 8) = bw1;
        __syncthreads();
        if (k0 + 32 < CCH) {           // issue next tile early; hides L2 latency
            aw0 = *(const uint4*)(wp + k0 + 32);
            aw1 = *(const uint4*)(wp + k0 + 40);
            bw0 = *(const uint4*)(ap + k0 + 32);
            bw1 = *(const uint4*)(ap + k0 + 40);
        }
        bf16x8 af[4], bfr[4];
        #pragma unroll
        for (int mi = 0; mi < 4; mi++)
            af[mi] = *(const bf16x8*)&As[(mo + mi*16 + lm) * 40 + quad * 8];
        #pragma unroll
        for (int ni = 0; ni < 4; ni++)
            bfr[ni] = *(const bf16x8*)&Bs[(no + ni*16 + lm) * 40 + quad * 8];
        __builtin_amdgcn_s_setprio(1);
        #pragma unroll
        for (int mi = 0; mi < 4; mi++)
            #pragma unroll
            for (int ni = 0; ni < 4; ni++)
                acc[mi][ni] = __builtin_amdgcn_mfma_f32_16x16x32_bf16(
                    af[mi], bfr[ni], acc[mi][ni], 0, 0, 0);
        __builtin_amdgcn_s_setprio(0);
        __syncthreads();
    }

    const int region = m0 >> 9;   // 0=Q 1=K 2=V
    if (region < 2) {
        u16* Cb = smem;
        #pragma unroll
        for (int mi = 0; mi < 4; mi++) {
            f32x4 bv = *(const f32x4*)&bias[m0 + mo + mi*16 + quad*4];
            #pragma unroll
            for (int ni = 0; ni < 4; ni++) {
                int colp = no + ni*16 + lm;
                int rowb = mo + mi*16 + quad*4;
                #pragma unroll
                for (int r = 0; r < 4; r++)
                    Cb[colp * 136 + rowb + r] = f2bu(acc[mi][ni][r] + bv[r]);
            }
        }
        __syncthreads();
        int prow = tid >> 1, half = tid & 1;
        u16* base = (region == 0) ? qT : kT;
        u16* dst = base + ((size_t)b * PP + p0 + prow) * 512 + (m0 & 511) + half * 64;
        const u16* src = &Cb[prow * 136 + half * 64];
        #pragma unroll
        for (int i = 0; i < 8; i++)
            *(uint4*)(dst + i * 8) = *(const uint4*)(src + i * 8);
    } else {
        u16* Cb = smem;
        #pragma unroll
        for (int mi = 0; mi < 4; mi++) {
            f32x4 bv = *(const f32x4*)&bias[m0 + mo + mi*16 + quad*4];
            #pragma unroll
            for (int ni = 0; ni < 4; ni++) {
                int colp = no + ni*16 + lm;
                int rowb = mo + mi*16 + quad*4;
                #pragma unroll
                for (int r = 0; r < 4; r++)
                    Cb[(rowb + r) * 136 + colp] = f2bu(acc[mi][ni][r] + bv[r]);
            }
        }
        __syncthreads();
        int row = tid >> 1, half = tid & 1;
        u16* dst = v + ((size_t)b * 512 + (m0 - 1024) + row) * PP + p0 + half * 64;
        const u16* src = &Cb[row * 136 + half * 64];
        #pragma unroll
        for (int i = 0; i < 8; i++)
            *(uint4*)(dst + i * 8) = *(const uint4*)(src + i * 8);
    }
}

// ---------------------------------------------------------------------------
// Kernel 5: MFMA flash attention.
// R9: q-tile 128, 8 waves (512 thr); wave w owns q rows w*16..w*16+15.
//   LDS: Ps [128][136] u16 (34816B) | Ks [128][72] (18432B) |
//        Vs [64][136]  (17408B)  -> 70656B total => 2 blocks/CU, 16 waves/CU.
//   T14: next K/V tile global->reg issued right after staging barrier;
//        latency hides under QK^T+softmax+PV.
//   softmax in exp2 domain (scale folds 0.125*log2e); raw v_exp_f32.
//   Wave-locality (validated R6/R8): Q staging, P round-trip, epilogue all
//   touch only wave-w rows of Ps; DS in-order per wave -> no barrier needed.
// ---------------------------------------------------------------------------
__launch_bounds__(512, 4)
__global__ void fattn_k(const u16* __restrict__ qT, const u16* __restrict__ kT,
                        const u16* __restrict__ v, u16* __restrict__ ao) {
    __shared__ __align__(16) u16 Ps[128 * 136];
    __shared__ __align__(16) u16 Ks[128 * 72];
    __shared__ __align__(16) u16 Vs[64 * 136];
    const int tid = threadIdx.x;
    const int q0 = blockIdx.x * 128;
    const int h  = blockIdx.y;
    const int b  = blockIdx.z;
    const int w = tid >> 6, l = tid & 63, quad = l >> 4, lm = l & 15;

    // stage Q (wave-local rows): lane -> row w*16+(l>>2), 16-u16 chunk (l&3)
    {
        int r = w * 16 + (l >> 2), c = (l & 3) * 16;
        const u16* src = qT + ((size_t)b * PP + q0 + r) * 512 + h * 64 + c;
        *(uint4*)&Ps[r * 136 + c]     = *(const uint4*)src;
        *(uint4*)&Ps[r * 136 + c + 8] = *(const uint4*)(src + 8);
    }
    // wave-local read-after-write: DS in-order per wave, no barrier
    bf16x8 qf0 = *(const bf16x8*)&Ps[(w * 16 + lm) * 136 + quad * 8];
    bf16x8 qf1 = *(const bf16x8*)&Ps[(w * 16 + lm) * 136 + 32 + quad * 8];

    f32x4 O[4] = {};
    float mrow[4] = {-3.0e38f, -3.0e38f, -3.0e38f, -3.0e38f};
    float lrow[4] = {};

    const int ksr = tid >> 2, ksc = (tid & 3) * 16;   // Ks: 4 thr/row, 16 u16
    const int vsr = tid >> 3, vsc = (tid & 7) * 16;   // Vs: 8 thr/row, 16 u16

    // T14 prologue: tile 0 into registers
    uint4 ka, kb, va, vb;
    {
        const u16* ksrc = kT + ((size_t)b * PP + ksr) * 512 + h * 64 + ksc;
        ka = *(const uint4*)ksrc; kb = *(const uint4*)(ksrc + 8);
        const u16* vsrc = v + ((size_t)b * 512 + h * 64 + vsr) * PP + vsc;
        va = *(const uint4*)vsrc; vb = *(const uint4*)(vsrc + 8);
    }

    for (int j0 = 0; j0 < PP; j0 += 128) {
        __syncthreads();   // previous iter's Ks/Vs reads done
        *(uint4*)&Ks[ksr * 72 + ksc]      = ka;
        *(uint4*)&Ks[ksr * 72 + ksc + 8]  = kb;
        *(uint4*)&Vs[vsr * 136 + vsc]     = va;
        *(uint4*)&Vs[vsr * 136 + vsc + 8] = vb;
        __syncthreads();   // staging visible to all waves

        // T14: issue next tile's global loads now; ~300cy latency hides
        // under the ~1500cy of QK^T + softmax + PV below.
        if (j0 + 128 < PP) {
            const u16* ksrc = kT + ((size_t)b * PP + j0 + 128 + ksr) * 512 + h * 64 + ksc;
            ka = *(const uint4*)ksrc; kb = *(const uint4*)(ksrc + 8);
            const u16* vsrc = v + ((size_t)b * 512 + h * 64 + vsr) * PP + j0 + 128 + vsc;
            va = *(const uint4*)vsrc; vb = *(const uint4*)(vsrc + 8);
        }

        // S = Q.K^T : 8 j-subtiles x (k=64 -> 2 MFMAs)
        f32x4 s[8];
        __builtin_amdgcn_s_setprio(1);
        #pragma unroll
        for (int ni = 0; ni < 8; ni++) {
            bf16x8 kf0 = *(const bf16x8*)&Ks[(ni*16 + lm) * 72 + quad * 8];
            bf16x8 kf1 = *(const bf16x8*)&Ks[(ni*16 + lm) * 72 + 32 + quad * 8];
            f32x4 z = {};
            z = __builtin_amdgcn_mfma_f32_16x16x32_bf16(qf0, kf0, z, 0, 0, 0);
            s[ni] = __builtin_amdgcn_mfma_f32_16x16x32_bf16(qf1, kf1, z, 0, 0, 0);
        }
        __builtin_amdgcn_s_setprio(0);

        // online softmax in exp2 domain (scale = 0.125 * log2(e)).
        // row = 16 lanes lm of this quad; P -> Ps (wave-local)
        #pragma unroll
        for (int r = 0; r < 4; r++) {
            float e[8];
            #pragma unroll
            for (int ni = 0; ni < 8; ni++) e[ni] = s[ni][r] * 0.18033688011f;
            float tm = fmaxf(fmaxf(fmaxf(e[0], e[1]), fmaxf(e[2], e[3])),
                             fmaxf(fmaxf(e[4], e[5]), fmaxf(e[6], e[7])));
            tm = fmaxf(tm, __shfl_xor(tm, 1));
            tm = fmaxf(tm, __shfl_xor(tm, 2));
            tm = fmaxf(tm, __shfl_xor(tm, 4));
            tm = fmaxf(tm, __shfl_xor(tm, 8));
            float mnew  = fmaxf(mrow[r], tm);
            float alpha = __builtin_amdgcn_exp2f(mrow[r] - mnew);
            mrow[r] = mnew;
            float ts = 0.f;
            int qq = (w * 16 + quad * 4 + r) * 136 + lm;
            #pragma unroll
            for (int ni = 0; ni < 8; ni++) {
                float p = __builtin_amdgcn_exp2f(e[ni] - mnew);
                ts += p;
                Ps[qq + ni * 16] = f2bu(p);
            }
            ts += __shfl_xor(ts, 1);
            ts += __shfl_xor(ts, 2);
            ts += __shfl_xor(ts, 4);
            ts += __shfl_xor(ts, 8);
            lrow[r] = lrow[r] * alpha + ts;
            O[0][r] *= alpha; O[1][r] *= alpha; O[2][r] *= alpha; O[3][r] *= alpha;
        }
        // no barrier: P write/read is wave-local, DS in-order

        // O += P.V : 4 k-frags (j) x 4 d-subtiles
        __builtin_amdgcn_s_setprio(1);
        #pragma unroll
        for (int kf = 0; kf < 4; kf++) {
            bf16x8 pf = *(const bf16x8*)&Ps[(w*16 + lm) * 136 + kf * 32 + quad * 8];
            #pragma unroll
            for (int nd = 0; nd < 4; nd++) {
                bf16x8 vf = *(const bf16x8*)&Vs[(nd*16 + lm) * 136 + kf * 32 + quad * 8];
                O[nd] = __builtin_amdgcn_mfma_f32_16x16x32_bf16(pf, vf, O[nd], 0, 0, 0);
            }
        }
        __builtin_amdgcn_s_setprio(0);
    }

    // epilogue (wave-local): normalize, O -> Ps [q][d], coalesced store
    #pragma unroll
    for (int r = 0; r < 4; r++) {
        float rinv = 1.f / lrow[r];
        int qq = (w * 16 + quad * 4 + r) * 136 + lm;
        Ps[qq]      = f2bu(O[0][r] * rinv);
        Ps[qq + 16] = f2bu(O[1][r] * rinv);
        Ps[qq + 32] = f2bu(O[2][r] * rinv);
        Ps[qq + 48] = f2bu(O[3][r] * rinv);
    }
    {
        int r = w * 16 + (l >> 2), c = (l & 3) * 16;
        u16* dst = ao + ((size_t)b * PP + q0 + r) * 512 + h * 64 + c;
        *(uint4*)dst       = *(const uint4*)&Ps[r * 136 + c];
        *(uint4*)(dst + 8) = *(const uint4*)&Ps[r * 136 + c + 8];
    }
}

// ---------------------------------------------------------------------------
// Kernel 6: out-proj MFMA GEMM + bias + residual, f32 out.
// R9: next-k reg prefetch + setprio.
// ---------------------------------------------------------------------------
__launch_bounds__(256)
__global__ void mgemm_out_k(const u16* __restrict__ Wb, const float* __restrict__ bias,
                            const u16* __restrict__ actT, const float* __restrict__ resid,
                            float* __restrict__ out) {
    __shared__ __align__(16) u16 smem[10240];
    u16* As = smem;
    u16* Bs = smem + 5120;
    const int tid = threadIdx.x;
    const int p0 = blockIdx.x * 128;
    const int m0 = blockIdx.y * 128;
    const int b  = blockIdx.z;
    const int w = tid >> 6, l = tid & 63, quad = l >> 4, lm = l & 15;
    const int mo = (w >> 1) * 64, no = (w & 1) * 64;

    f32x4 acc[4][4] = {};

    const int srow = tid >> 1, sks = (tid & 1) << 4;
    const u16* wp = Wb + (size_t)(m0 + srow) * CCH + sks;
    const u16* ap = actT + (size_t)b * PP * CCH + (size_t)(p0 + srow) * CCH + sks;
    u16* asw = &As[srow * 40 + sks];
    u16* bsw = &Bs[srow * 40 + sks];

    uint4 aw0 = *(const uint4*)(wp);
    uint4 aw1 = *(const uint4*)(wp + 8);
    uint4 bw0 = *(const uint4*)(ap);
    uint4 bw1 = *(const uint4*)(ap + 8);

    for (int k0 = 0; k0 < CCH; k0 += 32) {
        *(uint4*)asw = aw0;  *(uint4*)(asw + 8) = aw1;
        *(uint4*)bsw = bw0;  *(uint4*)(bsw + 8) = bw1;
        __syncthreads();
        if (k0 + 32 < CCH) {
            aw0 = *(const uint4*)(wp + k0 + 32);
            aw1 = *(const uint4*)(wp + k0 + 40);
            bw0 = *(const uint4*)(ap + k0 + 32);
            bw1 = *(const uint4*)(ap + k0 + 40);
        }
        bf16x8 af[4], bfr[4];
        #pragma unroll
        for (int mi = 0; mi < 4; mi++)
            af[mi] = *(const bf16x8*)&As[(mo + mi*16 + lm) * 40 + quad * 8];
        #pragma unroll
        for (int ni = 0; ni < 4; ni++)
            bfr[ni] = *(const bf16x8*)&Bs[(no + ni*16 + lm) * 40 + quad * 8];
        __builtin_amdgcn_s_setprio(1);
        #pragma unroll
        for (int mi = 0; mi < 4; mi++)
            #pragma unroll
            for (int ni = 0; ni < 4; ni++)
                acc[mi][ni] = __builtin_amdgcn_mfma_f32_16x16x32_bf16(
                    af[mi], bfr[ni], acc[mi][ni], 0, 0, 0);
        __builtin_amdgcn_s_setprio(0);
        __syncthreads();
    }

    #pragma unroll
    for (int mi = 0; mi < 4; mi++) {
        f32x4 bv = *(const f32x4*)&bias[m0 + mo + mi*16 + quad*4];
        #pragma unroll
        for (int ni = 0; ni < 4; ni++) {
            int p = p0 + no + ni*16 + lm;
            #pragma unroll
            for (int r = 0; r < 4; r++) {
                int m = m0 + mo + mi*16 + quad*4 + r;
                size_t idx = ((size_t)b * CCH + m) * PP + p;
                out[idx] = acc[mi][ni][r] + bv[r] + resid[idx];
            }
        }
    }
}

// ---------------------------------------------------------------------------
extern "C" void kernel_launch(void* const* d_in, const int* in_sizes, int n_in,
                              void* d_out, int out_size, void* d_ws, size_t ws_size,
                              hipStream_t stream) {
    const float* x     = (const float*)d_in[0];
    const float* gamma = (const float*)d_in[1];
    const float* beta  = (const float*)d_in[2];
    const float* w_qkv = (const float*)d_in[3];
    const float* b_qkv = (const float*)d_in[4];
    const float* w_out = (const float*)d_in[5];
    const float* b_out = (const float*)d_in[6];

    char* ws = (char*)d_ws;
    float* ps  = (float*)ws;                    // 512 f32 partial sums
    float* pss = (float*)(ws + 2048);           // 512 f32 partial sumsq
    u16* wqb = (u16*)(ws + 4096);               // 1536*512
    u16* wob = wqb + 1536 * 512;                // 512*512
    u16* xbt = wob + 512 * 512;                 // [b][p][c]  8.4M elems
    u16* ao  = xbt + (size_t)BB * PP * CCH;     // [b][p][c]  8.4M
    u16* qTb = ao  + (size_t)BB * PP * CCH;     // [b][p][512] 8.4M
    u16* kTb = qTb + (size_t)BB * PP * CCH;     // [b][p][512] 8.4M
    u16* vb  = kTb + (size_t)BB * PP * CCH;     // [b][512][p] 8.4M  (~86 MB)

    gn_stats_k<<<512, 256, 0, stream>>>(x, ps, pss);
    conv_x_k<<<dim3(16, 8, 16), 256, 0, stream>>>(x, ps, pss, gamma, beta, xbt);
    conv_w_k<<<1024, 256, 0, stream>>>(w_qkv, w_out, wqb, wob);
    mgemm_qkv_k<<<dim3(8, 12, 16), 256, 0, stream>>>(wqb, b_qkv, xbt, qTb, kTb, vb);
    fattn_k<<<dim3(8, 8, 16), 512, 0, stream>>>(qTb, kTb, vb, ao);
    mgemm_out_k<<<dim3(8, 4, 16), 256, 0, stream>>>(wob, b_out, ao, x, (float*)d_out);
}

// Round 2
// 250.280 us; speedup vs baseline: 1.2380x; 1.0561x over previous
//
#include <hip/hip_runtime.h>
#include <hip/hip_bf16.h>

// B=16, C=512, H=W=32 -> P=1024 pixels, 8 groups (64 ch), 8 heads (hd=64).
// Inputs f32, output f32.  Internals bf16 + fp32 accum (validated R6/R8).
// R10: XCD-aware block swizzle (fattn + both GEMMs), Ps XOR bank-swizzle,
//      MFMA ones-column row-sum (replaces ts adds+shuffles), softmax scale
//      folded into Q epilogue, gn_stats+conv_w merged into one launch.
#define BB   16
#define CCH  512
#define PP   1024
#define NHD  8

typedef unsigned short u16;
typedef unsigned int   u32;
typedef __attribute__((ext_vector_type(8))) short bf16x8;   // 8 bf16 = 4 VGPR
typedef __attribute__((ext_vector_type(4))) float f32x4;

__device__ __forceinline__ u16 f2bu(float f) {
    __hip_bfloat16 h = __float2bfloat16(f);   // RNE
    return *reinterpret_cast<u16*>(&h);
}

// ---------------------------------------------------------------------------
// Kernel 1: merged pre-pass.  Blocks 0..511: per-(bg,part) stat partials.
// Blocks 512..1535: weight f32->bf16 conversion.
// ---------------------------------------------------------------------------
__launch_bounds__(256)
__global__ void pre_k(const float* __restrict__ x,
                      float* __restrict__ ps, float* __restrict__ pss,
                      const float* __restrict__ w1, const float* __restrict__ w2,
                      u16* __restrict__ d1, u16* __restrict__ d2) {
    int blk = blockIdx.x;
    if (blk < 512) {
        int bg = blk >> 2, part = blk & 3;
        const float4* xp = (const float4*)(x + (size_t)bg * 65536 + (size_t)part * 16384);
        float s = 0.f, ss = 0.f;
        for (int i = threadIdx.x; i < 4096; i += 256) {
            float4 v = xp[i];
            s  += v.x + v.y + v.z + v.w;
            ss += v.x*v.x + v.y*v.y + v.z*v.z + v.w*v.w;
        }
        __shared__ float sh[256], sq[256];
        sh[threadIdx.x] = s; sq[threadIdx.x] = ss;
        __syncthreads();
        for (int off = 128; off > 0; off >>= 1) {
            if (threadIdx.x < off) {
                sh[threadIdx.x] += sh[threadIdx.x + off];
                sq[threadIdx.x] += sq[threadIdx.x + off];
            }
            __syncthreads();
        }
        if (threadIdx.x == 0) {
            ps[blk]  = sh[0];
            pss[blk] = sq[0];
        }
    } else {
        int id = (blk - 512) * 256 + threadIdx.x;
        const float* s; u16* d; int off;
        if (id < 196608) { s = w1; d = d1; off = id * 4; }
        else             { s = w2; d = d2; off = (id - 196608) * 4; }
        float4 v = *(const float4*)(s + off);
        ushort4 o;
        o.x = f2bu(v.x); o.y = f2bu(v.y); o.z = f2bu(v.z); o.w = f2bu(v.w);
        *(ushort4*)(d + off) = o;
    }
}

// ---------------------------------------------------------------------------
// Kernel 2: GN-normalize + convert + transpose: x[b][c][p] f32 ->
// xbt[b][p][c] bf16.  Combines the 4 stat partials (uniform -> SGPR loads).
// ---------------------------------------------------------------------------
__launch_bounds__(256)
__global__ void conv_x_k(const float* __restrict__ x,
                         const float* __restrict__ ps, const float* __restrict__ pss,
                         const float* __restrict__ gamma, const float* __restrict__ beta,
                         u16* __restrict__ xbt) {
    __shared__ u16 T[64][73];
    const int tid = threadIdx.x;
    const int p0 = blockIdx.x * 64;
    const int c0 = blockIdx.y * 64;
    const int b  = blockIdx.z;
    const int bg = (b << 3) + (c0 >> 6);      // uniform per block
    float s4  = ps[bg*4]  + ps[bg*4+1]  + ps[bg*4+2]  + ps[bg*4+3];
    float ss4 = pss[bg*4] + pss[bg*4+1] + pss[bg*4+2] + pss[bg*4+3];
    float m   = s4 * (1.f / 65536.f);
    float var = ss4 * (1.f / 65536.f) - m * m;
    float rs  = rsqrtf(var + 1e-5f);
    {
        int ci = tid >> 2, psx = (tid & 3) * 16;
        int c = c0 + ci;
        float sc = rs * gamma[c];
        float sf = beta[c] - m * sc;
        const float* xp = x + ((size_t)(b * CCH + c)) * PP + p0 + psx;
        #pragma unroll
        for (int j4 = 0; j4 < 4; j4++) {
            float4 v = *(const float4*)(xp + j4 * 4);
            T[psx + j4*4 + 0][ci] = f2bu(v.x * sc + sf);
            T[psx + j4*4 + 1][ci] = f2bu(v.y * sc + sf);
            T[psx + j4*4 + 2][ci] = f2bu(v.z * sc + sf);
            T[psx + j4*4 + 3][ci] = f2bu(v.w * sc + sf);
        }
    }
    __syncthreads();
    {
        int pi = tid >> 2, cs = (tid & 3) * 16;
        u16* dst = xbt + ((size_t)(b * PP) + p0 + pi) * CCH + c0 + cs;
        #pragma unroll
        for (int j4 = 0; j4 < 4; j4++) {
            ushort4 o;
            o.x = T[pi][cs + j4*4 + 0]; o.y = T[pi][cs + j4*4 + 1];
            o.z = T[pi][cs + j4*4 + 2]; o.w = T[pi][cs + j4*4 + 3];
            *(ushort4*)(dst + j4 * 4) = o;
        }
    }
}

// ---------------------------------------------------------------------------
// Kernel 4: qkv MFMA GEMM.  R10: XCD swizzle (2 batches per XCD so actT+W
// stay in one L2); Q output pre-scaled by 0.125*log2e for exp2-domain attn.
// ---------------------------------------------------------------------------
__launch_bounds__(256)
__global__ void mgemm_qkv_k(const u16* __restrict__ Wb, const float* __restrict__ bias,
                            const u16* __restrict__ actT,
                            u16* __restrict__ qT, u16* __restrict__ kT,
                            u16* __restrict__ v) {
    __shared__ __align__(16) u16 smem[17408];    // staging 2x5120 | Cb 128x136
    u16* As = smem;                              // [128][40]
    u16* Bs = smem + 5120;                       // [128][40]
    const int tid = threadIdx.x;
    // XCD swizzle: nwg=1536, 192/XCD, 96 blocks (12m x 8p) per batch.
    const int id = blockIdx.x;
    const int wk = (id & 7) * 192 + (id >> 3);
    const int b  = wk / 96;
    const int wi = wk % 96;
    const int m0 = (wi >> 3) * 128;
    const int p0 = (wi & 7) * 128;
    const int w = tid >> 6, l = tid & 63, quad = l >> 4, lm = l & 15;
    const int mo = (w >> 1) * 64, no = (w & 1) * 64;

    f32x4 acc[4][4] = {};

    const int srow = tid >> 1, sks = (tid & 1) << 4;
    const u16* wp = Wb + (size_t)(m0 + srow) * CCH + sks;
    const u16* ap = actT + (size_t)b * PP * CCH + (size_t)(p0 + srow) * CCH + sks;
    u16* asw = &As[srow * 40 + sks];
    u16* bsw = &Bs[srow * 40 + sks];

    uint4 aw0 = *(const uint4*)(wp);
    uint4 aw1 = *(const uint4*)(wp + 8);
    uint4 bw0 = *(const uint4*)(ap);
    uint4 bw1 = *(const uint4*)(ap + 8);

    for (int k0 = 0; k0 < CCH; k0 += 32) {
        *(uint4*)asw = aw0;  *(uint4*)(asw + 8) = aw1;
        *(uint4*)bsw = bw0;  *(uint4*)(bsw + 8) = bw1;
        __syncthreads();
        if (k0 + 32 < CCH) {           // issue next tile early; hides L2 latency
            aw0 = *(const uint4*)(wp + k0 + 32);
            aw1 = *(const uint4*)(wp + k0 + 40);
            bw0 = *(const uint4*)(ap + k0 + 32);
            bw1 = *(const uint4*)(ap + k0 + 40);
        }
        bf16x8 af[4], bfr[4];
        #pragma unroll
        for (int mi = 0; mi < 4; mi++)
            af[mi] = *(const bf16x8*)&As[(mo + mi*16 + lm) * 40 + quad * 8];
        #pragma unroll
        for (int ni = 0; ni < 4; ni++)
            bfr[ni] = *(const bf16x8*)&Bs[(no + ni*16 + lm) * 40 + quad * 8];
        __builtin_amdgcn_s_setprio(1);
        #pragma unroll
        for (int mi = 0; mi < 4; mi++)
            #pragma unroll
            for (int ni = 0; ni < 4; ni++)
                acc[mi][ni] = __builtin_amdgcn_mfma_f32_16x16x32_bf16(
                    af[mi], bfr[ni], acc[mi][ni], 0, 0, 0);
        __builtin_amdgcn_s_setprio(0);
        __syncthreads();
    }

    const int region = m0 >> 9;   // 0=Q 1=K 2=V
    if (region < 2) {
        const float scl = (region == 0) ? 0.18033688011f : 1.0f;  // 0.125*log2e
        u16* Cb = smem;
        #pragma unroll
        for (int mi = 0; mi < 4; mi++) {
            f32x4 bv = *(const f32x4*)&bias[m0 + mo + mi*16 + quad*4];
            #pragma unroll
            for (int ni = 0; ni < 4; ni++) {
                int colp = no + ni*16 + lm;
                int rowb = mo + mi*16 + quad*4;
                #pragma unroll
                for (int r = 0; r < 4; r++)
                    Cb[colp * 136 + rowb + r] = f2bu((acc[mi][ni][r] + bv[r]) * scl);
            }
        }
        __syncthreads();
        int prow = tid >> 1, half = tid & 1;
        u16* base = (region == 0) ? qT : kT;
        u16* dst = base + ((size_t)b * PP + p0 + prow) * 512 + (m0 & 511) + half * 64;
        const u16* src = &Cb[prow * 136 + half * 64];
        #pragma unroll
        for (int i = 0; i < 8; i++)
            *(uint4*)(dst + i * 8) = *(const uint4*)(src + i * 8);
    } else {
        u16* Cb = smem;
        #pragma unroll
        for (int mi = 0; mi < 4; mi++) {
            f32x4 bv = *(const f32x4*)&bias[m0 + mo + mi*16 + quad*4];
            #pragma unroll
            for (int ni = 0; ni < 4; ni++) {
                int colp = no + ni*16 + lm;
                int rowb = mo + mi*16 + quad*4;
                #pragma unroll
                for (int r = 0; r < 4; r++)
                    Cb[(rowb + r) * 136 + colp] = f2bu(acc[mi][ni][r] + bv[r]);
            }
        }
        __syncthreads();
        int row = tid >> 1, half = tid & 1;
        u16* dst = v + ((size_t)b * 512 + (m0 - 1024) + row) * PP + p0 + half * 64;
        const u16* src = &Cb[row * 136 + half * 64];
        #pragma unroll
        for (int i = 0; i < 8; i++)
            *(uint4*)(dst + i * 8) = *(const uint4*)(src + i * 8);
    }
}

// ---------------------------------------------------------------------------
// Kernel 5: MFMA flash attention.
// R10: XCD swizzle (16 whole (b,h) pairs per XCD -> K/V fetched once from
//      HBM, reused from that XCD's L2);
//      Ps XOR swizzle col ^= ((row>>2)&3)<<4  (16-u16 granularity, keeps all
//      b128 accesses contiguous; spreads the P b16-writes over all 32 banks);
//      row-sum via MFMA ones-column (Osum) replaces ts adds+shuffles;
//      Q arrives pre-scaled (exp2 domain) from mgemm_qkv.
// ---------------------------------------------------------------------------
__launch_bounds__(512, 4)
__global__ void fattn_k(const u16* __restrict__ qT, const u16* __restrict__ kT,
                        const u16* __restrict__ v, u16* __restrict__ ao) {
    __shared__ __align__(16) u16 Ps[128 * 136];
    __shared__ __align__(16) u16 Ks[128 * 72];
    __shared__ __align__(16) u16 Vs[64 * 136];
    const int tid = threadIdx.x;
    // XCD swizzle: nwg=1024, 128/XCD, (b,h) pair = 8 consecutive work units.
    const int id = blockIdx.x;
    const int wk = ((id & 7) << 7) | (id >> 3);
    const int q0 = (wk & 7) * 128;
    const int pair = wk >> 3;
    const int h = pair & 7;
    const int b = pair >> 3;
    const int w = tid >> 6, l = tid & 63, quad = l >> 4, lm = l & 15;
    const int psw = ((lm >> 2) & 3) << 4;      // Ps col-swizzle for row w*16+lm

    // stage Q (wave-local rows): lane -> row w*16+(l>>2), 16-u16 chunk (l&3)
    {
        int r = w * 16 + (l >> 2), c = (l & 3) * 16;
        int swz = ((l >> 4) & 3) << 4;         // ((r>>2)&3)<<4
        const u16* src = qT + ((size_t)b * PP + q0 + r) * 512 + h * 64 + c;
        *(uint4*)&Ps[r * 136 + (c ^ swz)]     = *(const uint4*)src;
        *(uint4*)&Ps[r * 136 + (c ^ swz) + 8] = *(const uint4*)(src + 8);
    }
    // wave-local read-after-write: DS in-order per wave, no barrier
    bf16x8 qf0 = *(const bf16x8*)&Ps[(w * 16 + lm) * 136 + ((quad * 8) ^ psw)];
    bf16x8 qf1 = *(const bf16x8*)&Ps[(w * 16 + lm) * 136 + ((32 + quad * 8) ^ psw)];

    bf16x8 onesv;
    #pragma unroll
    for (int i = 0; i < 8; i++) onesv[i] = (short)0x3F80;   // bf16 1.0

    f32x4 O[4] = {};
    f32x4 Ol = {};                                  // ones-column row sums
    float mrow[4] = {-3.0e38f, -3.0e38f, -3.0e38f, -3.0e38f};

    const int ksr = tid >> 2, ksc = (tid & 3) * 16;   // Ks: 4 thr/row, 16 u16
    const int vsr = tid >> 3, vsc = (tid & 7) * 16;   // Vs: 8 thr/row, 16 u16

    // T14 prologue: tile 0 into registers
    uint4 ka, kb, va, vb;
    {
        const u16* ksrc = kT + ((size_t)b * PP + ksr) * 512 + h * 64 + ksc;
        ka = *(const uint4*)ksrc; kb = *(const uint4*)(ksrc + 8);
        const u16* vsrc = v + ((size_t)b * 512 + h * 64 + vsr) * PP + vsc;
        va = *(const uint4*)vsrc; vb = *(const uint4*)(vsrc + 8);
    }

    for (int j0 = 0; j0 < PP; j0 += 128) {
        __syncthreads();   // previous iter's Ks/Vs reads done
        *(uint4*)&Ks[ksr * 72 + ksc]      = ka;
        *(uint4*)&Ks[ksr * 72 + ksc + 8]  = kb;
        *(uint4*)&Vs[vsr * 136 + vsc]     = va;
        *(uint4*)&Vs[vsr * 136 + vsc + 8] = vb;
        __syncthreads();   // staging visible to all waves

        // T14: issue next tile's global loads now; latency hides under compute
        if (j0 + 128 < PP) {
            const u16* ksrc = kT + ((size_t)b * PP + j0 + 128 + ksr) * 512 + h * 64 + ksc;
            ka = *(const uint4*)ksrc; kb = *(const uint4*)(ksrc + 8);
            const u16* vsrc = v + ((size_t)b * 512 + h * 64 + vsr) * PP + j0 + 128 + vsc;
            va = *(const uint4*)vsrc; vb = *(const uint4*)(vsrc + 8);
        }

        // S = Q.K^T : 8 j-subtiles x (k=64 -> 2 MFMAs)   (exp2 domain already)
        f32x4 s[8];
        __builtin_amdgcn_s_setprio(1);
        #pragma unroll
        for (int ni = 0; ni < 8; ni++) {
            bf16x8 kf0 = *(const bf16x8*)&Ks[(ni*16 + lm) * 72 + quad * 8];
            bf16x8 kf1 = *(const bf16x8*)&Ks[(ni*16 + lm) * 72 + 32 + quad * 8];
            f32x4 z = {};
            z = __builtin_amdgcn_mfma_f32_16x16x32_bf16(qf0, kf0, z, 0, 0, 0);
            s[ni] = __builtin_amdgcn_mfma_f32_16x16x32_bf16(qf1, kf1, z, 0, 0, 0);
        }
        __builtin_amdgcn_s_setprio(0);

        // online softmax (row = 16 lanes lm of this quad); P -> Ps (wave-local,
        // col-swizzled: col = lm + 16*(ni^quad)).
        #pragma unroll
        for (int r = 0; r < 4; r++) {
            float tm = fmaxf(fmaxf(fmaxf(s[0][r], s[1][r]), fmaxf(s[2][r], s[3][r])),
                             fmaxf(fmaxf(s[4][r], s[5][r]), fmaxf(s[6][r], s[7][r])));
            tm = fmaxf(tm, __shfl_xor(tm, 1));
            tm = fmaxf(tm, __shfl_xor(tm, 2));
            tm = fmaxf(tm, __shfl_xor(tm, 4));
            tm = fmaxf(tm, __shfl_xor(tm, 8));
            float mnew  = fmaxf(mrow[r], tm);
            float alpha = __builtin_amdgcn_exp2f(mrow[r] - mnew);
            mrow[r] = mnew;
            int rowb = (w * 16 + quad * 4 + r) * 136 + lm;
            #pragma unroll
            for (int ni = 0; ni < 8; ni++) {
                float p = __builtin_amdgcn_exp2f(s[ni][r] - mnew);
                Ps[rowb + 16 * (ni ^ quad)] = f2bu(p);
            }
            O[0][r] *= alpha; O[1][r] *= alpha; O[2][r] *= alpha; O[3][r] *= alpha;
            Ol[r] *= alpha;
        }
        // no barrier: P write/read is wave-local, DS in-order

        // O += P.V : 4 k-frags (j) x 4 d-subtiles; Ol += P.1 (row sums)
        __builtin_amdgcn_s_setprio(1);
        #pragma unroll
        for (int kf = 0; kf < 4; kf++) {
            bf16x8 pf = *(const bf16x8*)&Ps[(w*16 + lm) * 136 + ((kf * 32 + quad * 8) ^ psw)];
            Ol = __builtin_amdgcn_mfma_f32_16x16x32_bf16(pf, onesv, Ol, 0, 0, 0);
            #pragma unroll
            for (int nd = 0; nd < 4; nd++) {
                bf16x8 vf = *(const bf16x8*)&Vs[(nd*16 + lm) * 136 + kf * 32 + quad * 8];
                O[nd] = __builtin_amdgcn_mfma_f32_16x16x32_bf16(pf, vf, O[nd], 0, 0, 0);
            }
        }
        __builtin_amdgcn_s_setprio(0);
    }

    // epilogue (wave-local): normalize, O -> Ps [q][d] (swizzled), store
    #pragma unroll
    for (int r = 0; r < 4; r++) {
        float rinv = 1.f / Ol[r];
        int rowb = (w * 16 + quad * 4 + r) * 136 + lm;
        Ps[rowb + 16 * (0 ^ quad)] = f2bu(O[0][r] * rinv);
        Ps[rowb + 16 * (1 ^ quad)] = f2bu(O[1][r] * rinv);
        Ps[rowb + 16 * (2 ^ quad)] = f2bu(O[2][r] * rinv);
        Ps[rowb + 16 * (3 ^ quad)] = f2bu(O[3][r] * rinv);
    }
    {
        int r = w * 16 + (l >> 2), c = (l & 3) * 16;
        int swz = ((l >> 4) & 3) << 4;
        u16* dst = ao + ((size_t)b * PP + q0 + r) * 512 + h * 64 + c;
        *(uint4*)dst       = *(const uint4*)&Ps[r * 136 + (c ^ swz)];
        *(uint4*)(dst + 8) = *(const uint4*)&Ps[r * 136 + (c ^ swz) + 8];
    }
}

// ---------------------------------------------------------------------------
// Kernel 6: out-proj MFMA GEMM + bias + residual, f32 out.  R10: XCD swizzle.
// ---------------------------------------------------------------------------
__launch_bounds__(256)
__global__ void mgemm_out_k(const u16* __restrict__ Wb, const float* __restrict__ bias,
                            const u16* __restrict__ actT, const float* __restrict__ resid,
                            float* __restrict__ out) {
    __shared__ __align__(16) u16 smem[10240];
    u16* As = smem;
    u16* Bs = smem + 5120;
    const int tid = threadIdx.x;
    // XCD swizzle: nwg=512, 64/XCD, 32 blocks (4m x 8p) per batch.
    const int id = blockIdx.x;
    const int wk = (id & 7) * 64 + (id >> 3);
    const int b  = wk >> 5;
    const int wi = wk & 31;
    const int m0 = (wi >> 3) * 128;
    const int p0 = (wi & 7) * 128;
    const int w = tid >> 6, l = tid & 63, quad = l >> 4, lm = l & 15;
    const int mo = (w >> 1) * 64, no = (w & 1) * 64;

    f32x4 acc[4][4] = {};

    const int srow = tid >> 1, sks = (tid & 1) << 4;
    const u16* wp = Wb + (size_t)(m0 + srow) * CCH + sks;
    const u16* ap = actT + (size_t)b * PP * CCH + (size_t)(p0 + srow) * CCH + sks;
    u16* asw = &As[srow * 40 + sks];
    u16* bsw = &Bs[srow * 40 + sks];

    uint4 aw0 = *(const uint4*)(wp);
    uint4 aw1 = *(const uint4*)(wp + 8);
    uint4 bw0 = *(const uint4*)(ap);
    uint4 bw1 = *(const uint4*)(ap + 8);

    for (int k0 = 0; k0 < CCH; k0 += 32) {
        *(uint4*)asw = aw0;  *(uint4*)(asw + 8) = aw1;
        *(uint4*)bsw = bw0;  *(uint4*)(bsw + 8) = bw1;
        __syncthreads();
        if (k0 + 32 < CCH) {
            aw0 = *(const uint4*)(wp + k0 + 32);
            aw1 = *(const uint4*)(wp + k0 + 40);
            bw0 = *(const uint4*)(ap + k0 + 32);
            bw1 = *(const uint4*)(ap + k0 + 40);
        }
        bf16x8 af[4], bfr[4];
        #pragma unroll
        for (int mi = 0; mi < 4; mi++)
            af[mi] = *(const bf16x8*)&As[(mo + mi*16 + lm) * 40 + quad * 8];
        #pragma unroll
        for (int ni = 0; ni < 4; ni++)
            bfr[ni] = *(const bf16x8*)&Bs[(no + ni*16 + lm) * 40 + quad * 8];
        __builtin_amdgcn_s_setprio(1);
        #pragma unroll
        for (int mi = 0; mi < 4; mi++)
            #pragma unroll
            for (int ni = 0; ni < 4; ni++)
                acc[mi][ni] = __builtin_amdgcn_mfma_f32_16x16x32_bf16(
                    af[mi], bfr[ni], acc[mi][ni], 0, 0, 0);
        __builtin_amdgcn_s_setprio(0);
        __syncthreads();
    }

    #pragma unroll
    for (int mi = 0; mi < 4; mi++) {
        f32x4 bv = *(const f32x4*)&bias[m0 + mo + mi*16 + quad*4];
        #pragma unroll
        for (int ni = 0; ni < 4; ni++) {
            int p = p0 + no + ni*16 + lm;
            #pragma unroll
            for (int r = 0; r < 4; r++) {
                int m = m0 + mo + mi*16 + quad*4 + r;
                size_t idx = ((size_t)b * CCH + m) * PP + p;
                out[idx] = acc[mi][ni][r] + bv[r] + resid[idx];
            }
        }
    }
}

// ---------------------------------------------------------------------------
extern "C" void kernel_launch(void* const* d_in, const int* in_sizes, int n_in,
                              void* d_out, int out_size, void* d_ws, size_t ws_size,
                              hipStream_t stream) {
    const float* x     = (const float*)d_in[0];
    const float* gamma = (const float*)d_in[1];
    const float* beta  = (const float*)d_in[2];
    const float* w_qkv = (const float*)d_in[3];
    const float* b_qkv = (const float*)d_in[4];
    const float* w_out = (const float*)d_in[5];
    const float* b_out = (const float*)d_in[6];

    char* ws = (char*)d_ws;
    float* ps  = (float*)ws;                    // 512 f32 partial sums
    float* pss = (float*)(ws + 2048);           // 512 f32 partial sumsq
    u16* wqb = (u16*)(ws + 4096);               // 1536*512
    u16* wob = wqb + 1536 * 512;                // 512*512
    u16* xbt = wob + 512 * 512;                 // [b][p][c]  8.4M elems
    u16* ao  = xbt + (size_t)BB * PP * CCH;     // [b][p][c]  8.4M
    u16* qTb = ao  + (size_t)BB * PP * CCH;     // [b][p][512] 8.4M
    u16* kTb = qTb + (size_t)BB * PP * CCH;     // [b][p][512] 8.4M
    u16* vb  = kTb + (size_t)BB * PP * CCH;     // [b][512][p] 8.4M  (~86 MB)

    pre_k<<<1536, 256, 0, stream>>>(x, ps, pss, w_qkv, w_out, wqb, wob);
    conv_x_k<<<dim3(16, 8, 16), 256, 0, stream>>>(x, ps, pss, gamma, beta, xbt);
    mgemm_qkv_k<<<1536, 256, 0, stream>>>(wqb, b_qkv, xbt, qTb, kTb, vb);
    fattn_k<<<1024, 512, 0, stream>>>(qTb, kTb, vb, ao);
    mgemm_out_k<<<512, 256, 0, stream>>>(wob, b_out, ao, x, (float*)d_out);
}